// Round 11
// baseline (104.194 us; speedup 1.0000x reference)
//
#include <hip/hip_runtime.h>
#include <hip/hip_fp16.h>
#include <cstdint>

#define B_SZ   1024
#define N_IN   256
#define NLAY   8
#define M_SZ   4096
#define K_SZ   16
// Max column ever READ is 257 + 7*4096 - 1 = 28928; layer-7 out goes to global.
#define NCOLS_LDS 28932
#define SCALE  4.9f
#define TPB    1024

// -SCALE * log2(e): sigmoid(SCALE*a) = 1 / (1 + 2^(-SCALE*log2e*a))
#define NEG_SCALE_LOG2E  (-7.069205700355921f)

// ---------------------------------------------------------------------------
// Prologue: pack (idx, fp16(W)) AND bank-schedule the 16 commutative k-slots
// per 64-lane m-group, minimizing the PER-INSTRUCTION MAX bank bucket
// (m136: cost tracks N-way; 2-way is free). R7's lockstep greedy reduced
// Sigma-conflicts 28% with zero time effect because 64 simultaneous commits
// against stale counters left the max buckets intact.
//
// This version arbitrates same-cell collisions through atomicAdd's RETURN
// VALUE: attempt the min-loaded available slot; if old >= cap the lane
// retracts (atomicSub) and retries at a relaxed cap (2,3,4,...). Guaranteed
// termination (cap reaches 65 > any possible count; #items == #slots per
// lane). Deterministic: in-wave same-address atomic ordering is fixed
// hardware lane arbitration (R6/R7 gave byte-identical counters).
// ---------------------------------------------------------------------------
__global__ __launch_bounds__(256)
void sched_pack_kernel(const int* __restrict__ edge_idx,
                       const float* __restrict__ W,
                       uint32_t* __restrict__ packed) {
    __shared__ uint32_t cnt[4][16][32];   // [wave][slot][bank]

    const int wave = threadIdx.x >> 6;
    const int lane = threadIdx.x & 63;
    const int g    = blockIdx.x * 4 + wave;      // 512 groups total
    const int l    = g >> 6;
    const int mblk = g & 63;
    const int m    = mblk * 64 + lane;
    const int base = (l * M_SZ + m) * K_SZ;

    int   idxv[16];
    float wv[16];
    const int4*   ip = reinterpret_cast<const int4*>(edge_idx + base);
    const float4* wp = reinterpret_cast<const float4*>(W + base);
    #pragma unroll
    for (int j = 0; j < 4; ++j) {
        int4   ii = ip[j];
        float4 ww = wp[j];
        idxv[4*j+0] = ii.x; idxv[4*j+1] = ii.y; idxv[4*j+2] = ii.z; idxv[4*j+3] = ii.w;
        wv[4*j+0]   = ww.x; wv[4*j+1]   = ww.y; wv[4*j+2]   = ww.z; wv[4*j+3]   = ww.w;
    }

    uint32_t* cw = &cnt[wave][0][0];
    #pragma unroll
    for (int s = 0; s < 8; ++s) cw[lane + s * 64] = 0;
    __syncthreads();

    uint32_t am = 0;   // slots used by this lane
    uint32_t dm = 0;   // items assigned
    for (int cap = 2; cap <= 65; ++cap) {
        if (dm == 0xFFFFu) break;
        for (int k = 0; k < 16; ++k) {
            if ((dm >> k) & 1u) continue;
            const int b = idxv[k] & 31;
            uint32_t bl = 0xFFFFFFFFu;
            int      best = 0;
            #pragma unroll
            for (int s = 0; s < 16; ++s) {
                uint32_t c = cnt[wave][s][b];
                c = ((am >> s) & 1u) ? 0xFFFFFFFFu : c;
                if (c < bl) { bl = c; best = s; }
            }
            if (bl >= (uint32_t)cap) continue;           // no room at this cap
            uint32_t old = atomicAdd(&cnt[wave][best][b], 1u);
            if (old >= (uint32_t)cap) {                  // lost the race: retract
                atomicSub(&cnt[wave][best][b], 1u);
                continue;
            }
            am |= 1u << best;
            dm |= 1u << k;
            uint32_t pkw = ((uint32_t)idxv[k] & 0xFFFFu) |
                           ((uint32_t)__half_as_ushort(__float2half_rn(wv[k])) << 16);
            packed[base + best] = pkw;
        }
    }
}

// ---------------------------------------------------------------------------
// Main kernel: one block = 2 batch rows; activation history as half2 in LDS
// (115,728 B; lo = row b0, hi = row b0+1). R5's compiler-scheduled body
// (known-good 77 us) + exp2/rcp sigmoid. The packed table is slot-permuted
// per 64-lane group for bank balance; the k-sum is commutative so the main
// kernel is unchanged.
// ---------------------------------------------------------------------------
template <bool PACKED>
__global__ __launch_bounds__(TPB, 4)
void ffn_kernel(const float* __restrict__ x,
                const uint32_t* __restrict__ packed,
                const int* __restrict__ edge_idx,
                const float* __restrict__ W,
                float* __restrict__ out) {
    __shared__ uint32_t vals[NCOLS_LDS];

    const int tid = threadIdx.x;
    const int b0  = blockIdx.x * 2;
    const float* __restrict__ x0 = x + (size_t)b0 * N_IN;
    const float* __restrict__ x1 = x0 + N_IN;

    for (int j = tid; j <= N_IN; j += TPB) {
        float v0 = (j < N_IN) ? x0[j] : 1.0f;
        float v1 = (j < N_IN) ? x1[j] : 1.0f;
        __half2 h2 = __floats2half2_rn(v0, v1);
        vals[j] = *reinterpret_cast<uint32_t*>(&h2);
    }
    __syncthreads();

    const int base = N_IN + 1;
    for (int l = 0; l < NLAY; ++l) {
        for (int i = 0; i < M_SZ / TPB; ++i) {
            const int m = tid + i * TPB;
            float acc0 = 0.f, acc1 = 0.f;

            if (PACKED) {
                const uint4* p4 =
                    reinterpret_cast<const uint4*>(packed + ((size_t)l * M_SZ + m) * K_SZ);
                uint4 pw[4];
                #pragma unroll
                for (int j = 0; j < 4; ++j) pw[j] = p4[j];
                #pragma unroll
                for (int j = 0; j < 4; ++j) {
                    uint32_t words[4] = {pw[j].x, pw[j].y, pw[j].z, pw[j].w};
                    #pragma unroll
                    for (int q = 0; q < 4; ++q) {
                        uint32_t p = words[q];
                        uint32_t v = vals[p & 0xFFFFu];
                        float wf = __half2float(__ushort_as_half((unsigned short)(p >> 16)));
                        __half2 h2 = *reinterpret_cast<__half2*>(&v);
                        acc0 = fmaf(__low2float(h2),  wf, acc0);
                        acc1 = fmaf(__high2float(h2), wf, acc1);
                    }
                }
            } else {
                const int4*   i4 = reinterpret_cast<const int4*>(edge_idx + ((size_t)l * M_SZ + m) * K_SZ);
                const float4* w4 = reinterpret_cast<const float4*>(W + ((size_t)l * M_SZ + m) * K_SZ);
                #pragma unroll
                for (int j = 0; j < 4; ++j) {
                    int4   ii = i4[j];
                    float4 ww = w4[j];
                    int   idxs[4] = {ii.x, ii.y, ii.z, ii.w};
                    float wts[4]  = {ww.x, ww.y, ww.z, ww.w};
                    #pragma unroll
                    for (int q = 0; q < 4; ++q) {
                        uint32_t v = vals[idxs[q]];
                        __half2 h2 = *reinterpret_cast<__half2*>(&v);
                        acc0 = fmaf(__low2float(h2),  wts[q], acc0);
                        acc1 = fmaf(__high2float(h2), wts[q], acc1);
                    }
                }
            }

            float e0 = __builtin_amdgcn_exp2f(NEG_SCALE_LOG2E * acc0);
            float e1 = __builtin_amdgcn_exp2f(NEG_SCALE_LOG2E * acc1);
            float s0 = __builtin_amdgcn_rcpf(1.0f + e0);
            float s1 = __builtin_amdgcn_rcpf(1.0f + e1);

            if (l < NLAY - 1) {
                __half2 h2 = __floats2half2_rn(s0, s1);
                vals[base + l * M_SZ + m] = *reinterpret_cast<uint32_t*>(&h2);
            } else {
                out[(size_t)b0 * M_SZ + m]       = s0;
                out[(size_t)(b0 + 1) * M_SZ + m] = s1;
            }
        }
        __syncthreads();
    }
}

extern "C" void kernel_launch(void* const* d_in, const int* in_sizes, int n_in,
                              void* d_out, int out_size, void* d_ws, size_t ws_size,
                              hipStream_t stream) {
    const float* x        = (const float*)d_in[0];
    const float* W        = (const float*)d_in[1];
    const int*   edge_idx = (const int*)d_in[2];
    float*       out      = (float*)d_out;

    const int n = NLAY * M_SZ * K_SZ;  // 524288 packed words = 2 MB
    if (ws_size >= (size_t)n * sizeof(uint32_t)) {
        uint32_t* packed = (uint32_t*)d_ws;
        // 512 groups (l, mblk), one wave each, 4 waves per block.
        sched_pack_kernel<<<128, 256, 0, stream>>>(edge_idx, W, packed);
        ffn_kernel<true><<<B_SZ / 2, TPB, 0, stream>>>(x, packed, nullptr, nullptr, out);
    } else {
        ffn_kernel<false><<<B_SZ / 2, TPB, 0, stream>>>(x, nullptr, edge_idx, W, out);
    }
}

// Round 12
// 80.679 us; speedup vs baseline: 1.2915x; 1.2915x over previous
//
#include <hip/hip_runtime.h>
#include <hip/hip_fp16.h>
#include <cstdint>

#define B_SZ   1024
#define N_IN   256
#define NLAY   8
#define M_SZ   4096
#define K_SZ   16
// Max column ever READ is 257 + 7*4096 - 1 = 28928; layer-7 out goes to global.
#define NCOLS_LDS 28932
#define SCALE  4.9f
#define TPB    1024

// -SCALE * log2(e): sigmoid(SCALE*a) = 1 / (1 + 2^(-SCALE*log2e*a))
#define NEG_SCALE_LOG2E  (-7.069205700355921f)

// ---------------------------------------------------------------------------
// Prologue: pack (idx, fp16(W)) into one u32 (idx low16, w high16).
// Identity slot order: R7/R11 proved bank-rebalancing the slots reduces the
// SQ_LDS_BANK_CONFLICT counter 28% with ZERO time effect — per-instruction
// cost is pinned by the ~10.6 cy divergent-address phase, not by bank
// serialization (max bucket ~6 < address-phase length). Plain pack is 0.4 us.
// ---------------------------------------------------------------------------
__global__ void pack_kernel(const int* __restrict__ edge_idx,
                            const float* __restrict__ W,
                            uint32_t* __restrict__ packed, int n) {
    int i = blockIdx.x * blockDim.x + threadIdx.x;
    if (i < n) {
        uint32_t id = (uint32_t)edge_idx[i] & 0xFFFFu;
        __half h = __float2half_rn(W[i]);
        packed[i] = id | ((uint32_t)__half_as_ushort(h) << 16);
    }
}

// ---------------------------------------------------------------------------
// Main kernel: one block = 2 batch rows; activation history as half2 in LDS
// (115,728 B; lo = row b0, hi = row b0+1). 16 waves, 1 block/CU resident,
// 2 sequential block-passes per CU.
//
// Structure = R5's compiler-scheduled gather body (the known-good 77 us
// configuration; LLVM batches the 16 ds_reads per m and fuses cvt+fma into
// v_fma_mix). Rounds 5-11 established this is at the divergent-gather
// issue-rate floor: 16,384 random ds_read_b32 wave-instrs/CU x ~10.6 cy
// ~= 72 us, invariant to VALU work (27-48% swings), global prefetch,
// register pipelining, and two independent 28% bank-conflict reductions.
// Instruction-halving (b64, 4 rows) needs 231 KB LDS > 160 KB; global-path
// gathers are 64B-line amplified (>=4 GB L2); GEMM reformulation moves
// ~1 GB through L3. This shape is the roofline.
// ---------------------------------------------------------------------------
template <bool PACKED>
__global__ __launch_bounds__(TPB, 4)
void ffn_kernel(const float* __restrict__ x,
                const uint32_t* __restrict__ packed,
                const int* __restrict__ edge_idx,
                const float* __restrict__ W,
                float* __restrict__ out) {
    __shared__ uint32_t vals[NCOLS_LDS];

    const int tid = threadIdx.x;
    const int b0  = blockIdx.x * 2;
    const float* __restrict__ x0 = x + (size_t)b0 * N_IN;
    const float* __restrict__ x1 = x0 + N_IN;

    for (int j = tid; j <= N_IN; j += TPB) {
        float v0 = (j < N_IN) ? x0[j] : 1.0f;
        float v1 = (j < N_IN) ? x1[j] : 1.0f;
        __half2 h2 = __floats2half2_rn(v0, v1);
        vals[j] = *reinterpret_cast<uint32_t*>(&h2);
    }
    __syncthreads();

    const int base = N_IN + 1;
    for (int l = 0; l < NLAY; ++l) {
        for (int i = 0; i < M_SZ / TPB; ++i) {
            const int m = tid + i * TPB;
            float acc0 = 0.f, acc1 = 0.f;

            if (PACKED) {
                const uint4* p4 =
                    reinterpret_cast<const uint4*>(packed + ((size_t)l * M_SZ + m) * K_SZ);
                uint4 pw[4];
                #pragma unroll
                for (int j = 0; j < 4; ++j) pw[j] = p4[j];
                #pragma unroll
                for (int j = 0; j < 4; ++j) {
                    uint32_t words[4] = {pw[j].x, pw[j].y, pw[j].z, pw[j].w};
                    #pragma unroll
                    for (int q = 0; q < 4; ++q) {
                        uint32_t p = words[q];
                        uint32_t v = vals[p & 0xFFFFu];
                        float wf = __half2float(__ushort_as_half((unsigned short)(p >> 16)));
                        __half2 h2 = *reinterpret_cast<__half2*>(&v);
                        acc0 = fmaf(__low2float(h2),  wf, acc0);
                        acc1 = fmaf(__high2float(h2), wf, acc1);
                    }
                }
            } else {
                const int4*   i4 = reinterpret_cast<const int4*>(edge_idx + ((size_t)l * M_SZ + m) * K_SZ);
                const float4* w4 = reinterpret_cast<const float4*>(W + ((size_t)l * M_SZ + m) * K_SZ);
                #pragma unroll
                for (int j = 0; j < 4; ++j) {
                    int4   ii = i4[j];
                    float4 ww = w4[j];
                    int   idxs[4] = {ii.x, ii.y, ii.z, ii.w};
                    float wts[4]  = {ww.x, ww.y, ww.z, ww.w};
                    #pragma unroll
                    for (int q = 0; q < 4; ++q) {
                        uint32_t v = vals[idxs[q]];
                        __half2 h2 = *reinterpret_cast<__half2*>(&v);
                        acc0 = fmaf(__low2float(h2),  wts[q], acc0);
                        acc1 = fmaf(__high2float(h2), wts[q], acc1);
                    }
                }
            }

            float e0 = __builtin_amdgcn_exp2f(NEG_SCALE_LOG2E * acc0);
            float e1 = __builtin_amdgcn_exp2f(NEG_SCALE_LOG2E * acc1);
            float s0 = __builtin_amdgcn_rcpf(1.0f + e0);
            float s1 = __builtin_amdgcn_rcpf(1.0f + e1);

            if (l < NLAY - 1) {
                __half2 h2 = __floats2half2_rn(s0, s1);
                vals[base + l * M_SZ + m] = *reinterpret_cast<uint32_t*>(&h2);
            } else {
                out[(size_t)b0 * M_SZ + m]       = s0;
                out[(size_t)(b0 + 1) * M_SZ + m] = s1;
            }
        }
        // Layer 7 writes only to global memory - no barrier needed after it.
        if (l < NLAY - 1) __syncthreads();
    }
}

extern "C" void kernel_launch(void* const* d_in, const int* in_sizes, int n_in,
                              void* d_out, int out_size, void* d_ws, size_t ws_size,
                              hipStream_t stream) {
    const float* x        = (const float*)d_in[0];
    const float* W        = (const float*)d_in[1];
    const int*   edge_idx = (const int*)d_in[2];
    float*       out      = (float*)d_out;

    const int n = NLAY * M_SZ * K_SZ;  // 524288 packed words = 2 MB
    if (ws_size >= (size_t)n * sizeof(uint32_t)) {
        uint32_t* packed = (uint32_t*)d_ws;
        pack_kernel<<<(n + 255) / 256, 256, 0, stream>>>(edge_idx, W, packed, n);
        ffn_kernel<true><<<B_SZ / 2, TPB, 0, stream>>>(x, packed, nullptr, nullptr, out);
    } else {
        ffn_kernel<false><<<B_SZ / 2, TPB, 0, stream>>>(x, nullptr, edge_idx, W, out);
    }
}